// Round 1
// baseline (110.110 us; speedup 1.0000x reference)
//
#include <hip/hip_runtime.h>

// Problem constants (match reference)
#define S_DIM   2048
#define N_BATCH 32
#define NOUT    4
#define COUT    4
#define NCLS    10

#define ROWS_PER_BLOCK 32
#define BLOCKS_PER_IMG (S_DIM / ROWS_PER_BLOCK)   // 64
#define F4_PER_ROW     (S_DIM / 4)                // 512
#define F4_HALF        (F4_PER_ROW / 2)           // 256

// Kernel 1: per-image quadrant sums.
// Grid: (BLOCKS_PER_IMG, N_BATCH), block 256 threads.
// Block (rb, img) owns rows [rb*32, rb*32+32) of image img. All 32 rows are in
// the same top/bottom half (64 blocks, boundary at block 32). Thread t reads
// float4 t (left half, cols 0..1023) and t+256 (right half) of each row.
__global__ __launch_bounds__(256)
void quad_sums_kernel(const float* __restrict__ x, float* __restrict__ sums) {
    const int img  = blockIdx.y;
    const int rb   = blockIdx.x;
    const int tid  = threadIdx.x;
    const int row0 = rb * ROWS_PER_BLOCK;

    const float4* x4 = reinterpret_cast<const float4*>(
        x + (size_t)img * S_DIM * S_DIM);

    float accL = 0.f, accR = 0.f;
    #pragma unroll 4
    for (int r = 0; r < ROWS_PER_BLOCK; ++r) {
        const float4* rowp = x4 + (size_t)(row0 + r) * F4_PER_ROW;
        float4 a = rowp[tid];            // left half of row
        float4 b = rowp[tid + F4_HALF];  // right half of row
        accL += (a.x + a.y) + (a.z + a.w);
        accR += (b.x + b.y) + (b.z + b.w);
    }

    // wave (64-lane) butterfly reduce
    #pragma unroll
    for (int off = 32; off > 0; off >>= 1) {
        accL += __shfl_down(accL, off, 64);
        accR += __shfl_down(accR, off, 64);
    }

    __shared__ float sL[4], sR[4];
    const int wave = tid >> 6;
    if ((tid & 63) == 0) { sL[wave] = accL; sR[wave] = accR; }
    __syncthreads();

    if (tid == 0) {
        float tL = (sL[0] + sL[1]) + (sL[2] + sL[3]);
        float tR = (sR[0] + sR[1]) + (sR[2] + sR[3]);
        // quadrants: top-left=0, bottom-left=1, bottom-right=2, top-right=3
        const bool top = (row0 < (S_DIM / 2));
        const int qL = top ? 0 : 1;
        const int qR = top ? 3 : 2;
        atomicAdd(&sums[img * NOUT + qL], tL);
        atomicAdd(&sums[img * NOUT + qR], tR);
    }
}

// Kernel 2: weight-norm + per-node linear + FC head. One block, 320 threads
// (one per (n, class) output). Tiny.
__global__ __launch_bounds__(320)
void head_kernel(const float* __restrict__ sums,
                 const float* __restrict__ v,      // (4,4,1)
                 const float* __restrict__ g,      // (4,)
                 const float* __restrict__ b_fgl,  // (4,4)
                 const float* __restrict__ W_fc,   // (10,16)
                 const float* __restrict__ b_fc,   // (10,)
                 float* __restrict__ out) {        // (32,10)
    const int tid = threadIdx.x;
    if (tid >= N_BATCH * NCLS) return;
    const int n = tid / NCLS;
    const int k = tid % NCLS;

    float acc = b_fc[k];
    #pragma unroll
    for (int o = 0; o < NOUT; ++o) {
        float nv = 0.f;
        #pragma unroll
        for (int c = 0; c < COUT; ++c) nv += v[o * COUT + c] * v[o * COUT + c];
        const float scale = g[o] / sqrtf(nv);
        const float s = sums[n * NOUT + o];
        #pragma unroll
        for (int c = 0; c < COUT; ++c) {
            const float w = scale * v[o * COUT + c];
            const float h = s * w + b_fgl[o * COUT + c];
            acc += h * W_fc[k * (NOUT * COUT) + o * COUT + c];
        }
    }
    out[n * NCLS + k] = acc;
}

extern "C" void kernel_launch(void* const* d_in, const int* in_sizes, int n_in,
                              void* d_out, int out_size, void* d_ws, size_t ws_size,
                              hipStream_t stream) {
    const float* x     = (const float*)d_in[0];
    const float* v     = (const float*)d_in[1];
    const float* g     = (const float*)d_in[2];
    const float* b_fgl = (const float*)d_in[3];
    const float* W_fc  = (const float*)d_in[4];
    const float* b_fc  = (const float*)d_in[5];
    // d_in[6] = quads: deterministic function of indices; partition hardcoded.

    float* sums = (float*)d_ws;              // 32*4 floats
    float* out  = (float*)d_out;             // 32*10 floats

    hipMemsetAsync(sums, 0, N_BATCH * NOUT * sizeof(float), stream);

    dim3 grid(BLOCKS_PER_IMG, N_BATCH);
    quad_sums_kernel<<<grid, 256, 0, stream>>>(x, sums);

    head_kernel<<<1, 320, 0, stream>>>(sums, v, g, b_fgl, W_fc, b_fc, out);
}

// Round 3
// 86.286 us; speedup vs baseline: 1.2761x; 1.2761x over previous
//
#include <hip/hip_runtime.h>

// Problem constants (match reference)
#define S_DIM   2048
#define N_BATCH 32
#define NOUT    4
#define COUT    4
#define NCLS    10

#define ROWS_PER_BLOCK 32
#define BLOCKS_PER_IMG (S_DIM / ROWS_PER_BLOCK)   // 64
#define F4_PER_ROW     (S_DIM / 4)                // 512
#define F4_HALF        (F4_PER_ROW / 2)           // 256

// clang-native float4 so __builtin_nontemporal_load accepts the pointer
typedef float vfloat4 __attribute__((ext_vector_type(4)));

// Kernel 1: per-image, per-row-block partial sums (left half, right half).
// Grid: (BLOCKS_PER_IMG, N_BATCH), block 256 threads.
// Block (rb, img) owns rows [rb*32, rb*32+32); all 32 rows share the same
// top/bottom half (boundary at rb==32). Thread t covers float4 column t of
// the left half and t+256 of the right half, for rows r and r+16 per
// iteration -> 4 independent accumulators, 16 loads in flight at unroll 4.
// Writes one float2 partial per block to d_ws (no atomics, no memset needed).
__global__ __launch_bounds__(256)
void quad_sums_kernel(const float* __restrict__ x, float2* __restrict__ partials) {
    const int img  = blockIdx.y;
    const int rb   = blockIdx.x;
    const int tid  = threadIdx.x;
    const int row0 = rb * ROWS_PER_BLOCK;

    const vfloat4* x4 = reinterpret_cast<const vfloat4*>(
        x + (size_t)img * S_DIM * S_DIM);

    float aL0 = 0.f, aR0 = 0.f, aL1 = 0.f, aR1 = 0.f;
    #pragma unroll 4
    for (int r = 0; r < ROWS_PER_BLOCK / 2; ++r) {
        const vfloat4* p0 = x4 + (size_t)(row0 + r) * F4_PER_ROW;
        const vfloat4* p1 = x4 + (size_t)(row0 + r + 16) * F4_PER_ROW;
        vfloat4 a = __builtin_nontemporal_load(p0 + tid);
        vfloat4 b = __builtin_nontemporal_load(p0 + tid + F4_HALF);
        vfloat4 c = __builtin_nontemporal_load(p1 + tid);
        vfloat4 d = __builtin_nontemporal_load(p1 + tid + F4_HALF);
        aL0 += (a.x + a.y) + (a.z + a.w);
        aR0 += (b.x + b.y) + (b.z + b.w);
        aL1 += (c.x + c.y) + (c.z + c.w);
        aR1 += (d.x + d.y) + (d.z + d.w);
    }
    float accL = aL0 + aL1;
    float accR = aR0 + aR1;

    // wave (64-lane) butterfly reduce
    #pragma unroll
    for (int off = 32; off > 0; off >>= 1) {
        accL += __shfl_down(accL, off, 64);
        accR += __shfl_down(accR, off, 64);
    }

    __shared__ float sL[4], sR[4];
    const int wave = tid >> 6;
    if ((tid & 63) == 0) { sL[wave] = accL; sR[wave] = accR; }
    __syncthreads();

    if (tid == 0) {
        float2 p;
        p.x = (sL[0] + sL[1]) + (sL[2] + sL[3]);   // left-half sum of these rows
        p.y = (sR[0] + sR[1]) + (sR[2] + sR[3]);   // right-half sum
        partials[img * BLOCKS_PER_IMG + rb] = p;
    }
}

// Kernel 2: reduce partials -> quadrant sums, then weight-norm + per-node
// linear + FC head. One block, 384 threads. Tiny.
// Quadrants: 0=top-left, 1=bottom-left, 2=bottom-right, 3=top-right.
//   q0 = sum of .x over rb<32,  q1 = .x over rb>=32,
//   q2 = .y over rb>=32,        q3 = .y over rb<32.
__global__ __launch_bounds__(384)
void head_kernel(const float2* __restrict__ partials,
                 const float* __restrict__ v,      // (4,4,1)
                 const float* __restrict__ g,      // (4,)
                 const float* __restrict__ b_fgl,  // (4,4)
                 const float* __restrict__ W_fc,   // (10,16)
                 const float* __restrict__ b_fc,   // (10,)
                 float* __restrict__ out) {        // (32,10)
    __shared__ float sums_s[N_BATCH][NOUT];
    const int tid = threadIdx.x;

    if (tid < N_BATCH * NOUT) {
        const int n = tid >> 2;
        const int q = tid & 3;
        const int rb0   = (q == 1 || q == 2) ? 32 : 0;
        const bool useY = (q >= 2);
        float s = 0.f;
        #pragma unroll 8
        for (int i = 0; i < 32; ++i) {
            float2 p = partials[n * BLOCKS_PER_IMG + rb0 + i];
            s += useY ? p.y : p.x;
        }
        sums_s[n][q] = s;
    }
    __syncthreads();

    if (tid < N_BATCH * NCLS) {
        const int n = tid / NCLS;
        const int k = tid % NCLS;
        float acc = b_fc[k];
        #pragma unroll
        for (int o = 0; o < NOUT; ++o) {
            float nv = 0.f;
            #pragma unroll
            for (int c = 0; c < COUT; ++c) nv += v[o * COUT + c] * v[o * COUT + c];
            const float scale = g[o] / sqrtf(nv);
            const float s = sums_s[n][o];
            #pragma unroll
            for (int c = 0; c < COUT; ++c) {
                const float w = scale * v[o * COUT + c];
                const float h = s * w + b_fgl[o * COUT + c];
                acc += h * W_fc[k * (NOUT * COUT) + o * COUT + c];
            }
        }
        out[n * NCLS + k] = acc;
    }
}

extern "C" void kernel_launch(void* const* d_in, const int* in_sizes, int n_in,
                              void* d_out, int out_size, void* d_ws, size_t ws_size,
                              hipStream_t stream) {
    const float* x     = (const float*)d_in[0];
    const float* v     = (const float*)d_in[1];
    const float* g     = (const float*)d_in[2];
    const float* b_fgl = (const float*)d_in[3];
    const float* W_fc  = (const float*)d_in[4];
    const float* b_fc  = (const float*)d_in[5];
    // d_in[6] = quads: deterministic function of indices; partition hardcoded.

    float2* partials = (float2*)d_ws;   // 32*64 float2 = 16 KB, fully rewritten every call
    float*  out      = (float*)d_out;   // 32*10 floats

    dim3 grid(BLOCKS_PER_IMG, N_BATCH);
    quad_sums_kernel<<<grid, 256, 0, stream>>>(x, partials);

    head_kernel<<<1, 384, 0, stream>>>(partials, v, g, b_fgl, W_fc, b_fc, out);
}